// Round 12
// baseline (7243.609 us; speedup 1.0000x reference)
//
#include <hip/hip_runtime.h>

#define B_   128
#define T_   1024
#define DIN  256
#define H_   512
#define DOUT 128
#define NWG  256   // 128 column-groups (4 cols) x 2 batch-halves

typedef __attribute__((ext_vector_type(4))) float f32x4;
typedef __attribute__((ext_vector_type(8))) short bf16x8;
typedef __attribute__((ext_vector_type(4))) short bf16x4;

// ---- ws byte layout (R10-identical) ----
#define H0_OFF   0u                      // [2][64 g][128 b][8] bf16 = 256KB
#define H1_OFF   (256u << 10)            // same = 256KB
#define FIN_OFF  (512u << 10)            // [128][512] f32 = 256KB
#define FLG_OFF  (768u << 10)            // flags[256] @ 128B stride = 32KB
#define XB_OFF   (800u << 10)            // [1024][32 g][128 b][8] bf16 = 64MB
#define XB_BYTES ((size_t)T_ * 32 * 128 * 8 * 2)

__device__ __forceinline__ short f2bf(float f) {
  union { float f; unsigned u; } v; v.f = f;
  unsigned r = v.u + 0x7FFFu + ((v.u >> 16) & 1u);
  return (short)(r >> 16);
}
__device__ __forceinline__ float sigf(float x) { return 1.f / (1.f + __expf(-x)); }

// agent-scope coherent access (bypasses non-coherent per-XCD L2)
__device__ __forceinline__ void st_bf(short* p, short v) {
  __hip_atomic_store((unsigned short*)p, (unsigned short)v,
                     __ATOMIC_RELAXED, __HIP_MEMORY_SCOPE_AGENT);
}
__device__ __forceinline__ void st_f32(float* p, float v) {
  __hip_atomic_store(p, v, __ATOMIC_RELAXED, __HIP_MEMORY_SCOPE_AGENT);
}
__device__ __forceinline__ void st_u32(unsigned* p, unsigned v) {
  __hip_atomic_store(p, v, __ATOMIC_RELAXED, __HIP_MEMORY_SCOPE_AGENT);
}
__device__ __forceinline__ unsigned ld_u32(const unsigned* p) {
  return __hip_atomic_load(p, __ATOMIC_RELAXED, __HIP_MEMORY_SCOPE_AGENT);
}
// coherent 16B load, no wait (caller drains vmcnt before use)
__device__ __forceinline__ void ld16(bf16x8& d, const short* p) {
  asm volatile("global_load_dwordx4 %0, %1, off sc0 sc1" : "=v"(d) : "v"(p));
}

__global__ void lstm_init_kernel(void* ws) {
  int gid = blockIdx.x * blockDim.x + threadIdx.x;   // 131072 threads
  unsigned* p = (unsigned*)ws;                       // h0+h1 = 512KB
  __hip_atomic_store(p + gid, 0u, __ATOMIC_RELAXED, __HIP_MEMORY_SCOPE_AGENT);
  if (gid < 8192) {
    unsigned* f = (unsigned*)((char*)ws + FLG_OFF);
    __hip_atomic_store(f + gid, 0u, __ATOMIC_RELAXED, __HIP_MEMORY_SCOPE_AGENT);
  }
}

// x fp32 [B][T][DIN] -> xb bf16 fragment-major [T][32 g][128 b][8]
__global__ void xconv_kernel(const float* __restrict__ x, short* __restrict__ xb) {
  int blk = blockIdx.x;            // t*32 + g
  int t = blk >> 5, g = blk & 31;
  int b = threadIdx.x >> 1, hf = (threadIdx.x & 1) * 4;
  f32x4 v = *(const f32x4*)(x + ((size_t)b * T_ + t) * DIN + g * 8 + hf);
  bf16x4 o;
#pragma unroll
  for (int j = 0; j < 4; ++j) o[j] = f2bf(v[j]);
  *(bf16x4*)(xb + ((size_t)(t * 32 + g) * 128 + b) * 8 + hf) = o;
}

__global__ __launch_bounds__(256, 2) void lstm_coop_kernel(
    const float* __restrict__ x,
    const float* __restrict__ wih0, const float* __restrict__ whh0,
    const float* __restrict__ bih0, const float* __restrict__ bhh0,
    const float* __restrict__ wih1, const float* __restrict__ whh1,
    const float* __restrict__ bih1, const float* __restrict__ bhh1,
    const float* __restrict__ fcw,  const float* __restrict__ fcb,
    const short* __restrict__ xb,
    void* __restrict__ ws, float* __restrict__ out)
{
  __shared__ short sWih0[16][264];
  __shared__ short sWhh0[16][520];
  __shared__ short sWih1[16][520];
  __shared__ short sWhh1[16][520];
  __shared__ f32x4 sred[4][4][64];       // [src wave][btile][lane] = 16KB

  const int tid  = threadIdx.x;
  const int wg   = blockIdx.x;
  const int cgid = wg >> 1;
  const int bh   = wg & 1;
  const int j0   = cgid * 4;

  char* wsb = (char*)ws;
  short* h0buf = (short*)(wsb + H0_OFF);
  short* h1buf = (short*)(wsb + H1_OFF);
  float* h1fin = (float*)(wsb + FIN_OFF);
  unsigned* flags = (unsigned*)(wsb + FLG_OFF);
  unsigned* ownf  = flags + wg * 32;

  // weight slices -> LDS (R10-verified staging); row lr = 4*jj + gate
  for (int idx = tid; idx < 16 * DIN; idx += 256) {
    int lr = idx >> 8, k = idx & 255;
    int grow = (lr & 3) * H_ + j0 + (lr >> 2);
    sWih0[lr][k] = f2bf(wih0[(size_t)grow * DIN + k]);
  }
  for (int idx = tid; idx < 16 * H_; idx += 256) {
    int lr = idx >> 9, k = idx & 511;
    int grow = (lr & 3) * H_ + j0 + (lr >> 2);
    sWhh0[lr][k] = f2bf(whh0[(size_t)grow * H_ + k]);
    sWih1[lr][k] = f2bf(wih1[(size_t)grow * H_ + k]);
    sWhh1[lr][k] = f2bf(whh1[(size_t)grow * H_ + k]);
  }
  __syncthreads();

  const int lane = tid & 63;
  const int w    = tid >> 6;                // wave = K-quarter owner AND owned btile
  const int ln   = lane & 15;               // A row-in-tile / C col (batch)
  const int q    = lane >> 4;               // k-subblock / C row-group (jj)
  const int b    = bh * 64 + w * 16 + ln;   // owned batch row (same as R10 wid map)
  const int jj   = j0 + q;
  const int hwof = (jj >> 3) * 1024 + (jj & 7);

  // ---- A fragments -> persistent registers (wave's K-quarter; 14 frags) ----
  bf16x8 aIH0[2], aHH0[4], aIH1[4], aHH1[4];
#pragma unroll
  for (int s2 = 0; s2 < 2; ++s2)
    aIH0[s2] = *(const bf16x8*)(&sWih0[ln][(2 * w + s2) * 32 + q * 8]);
#pragma unroll
  for (int s = 0; s < 4; ++s) {
    aHH0[s] = *(const bf16x8*)(&sWhh0[ln][(4 * w + s) * 32 + q * 8]);
    aIH1[s] = *(const bf16x8*)(&sWih1[ln][(4 * w + s) * 32 + q * 8]);
    aHH1[s] = *(const bf16x8*)(&sWhh1[ln][(4 * w + s) * 32 + q * 8]);
  }

  f32x4 bias0v, bias1v;
#pragma unroll
  for (int g = 0; g < 4; ++g) {
    int rr = g * H_ + jj;
    bias0v[g] = bih0[rr] + bhh0[rr];
    bias1v[g] = bih1[rr] + bhh1[rr];
  }

  // x prefetch: wave's K-quarter (ks = 2w+s2) for all 4 btiles
  bf16x8 xp[2][4];
  auto xpref = [&](int t) {
#pragma unroll
    for (int s2 = 0; s2 < 2; ++s2) {
      const int g = q + 4 * (2 * w + s2);
#pragma unroll
      for (int bt = 0; bt < 4; ++bt) {
        const int bb = bh * 64 + bt * 16 + ln;
        if (xb) {
          xp[s2][bt] = *(const bf16x8*)(xb + ((size_t)(t * 32 + g) * 128 + bb) * 8);
        } else {
          const float* p = x + ((size_t)bb * T_ + t) * DIN + (2 * w + s2) * 32 + q * 8;
          f32x4 a = *(const f32x4*)p, b2 = *(const f32x4*)(p + 4);
          bf16x8 f;
#pragma unroll
          for (int j = 0; j < 4; ++j) { f[j] = f2bf(a[j]); f[4 + j] = f2bf(b2[j]); }
          xp[s2][bt] = f;
        }
      }
    }
  };
  xpref(0);

  float c0v = 0.f, c1v = 0.f;

  for (int r = 0; r <= T_; ++r) {
    const short* h0rd = h0buf + (r & 1) * 65536;
    short*       h0wr = h0buf + ((r + 1) & 1) * 65536;
    const short* h1rd = h1buf + (r & 1) * 65536;
    short*       h1wr = h1buf + ((r + 1) & 1) * 65536;

    // ---- coherent B loads: wave's K-quarter (ks = 4w+s) for all 4 btiles ----
    bf16x8 f0[4][4], f1[4][4];
#pragma unroll
    for (int bt = 0; bt < 4; ++bt) {
      const int bb = bh * 64 + bt * 16 + ln;
      const short* pb0 = h0rd + (size_t)bb * 8;
      const short* pb1 = h1rd + (size_t)bb * 8;
#pragma unroll
      for (int s = 0; s < 4; ++s) {
        const int g = q + 4 * (4 * w + s);
        ld16(f0[bt][s], pb0 + g * 1024);
        ld16(f1[bt][s], pb1 + g * 1024);
      }
    }
    asm volatile("s_waitcnt vmcnt(0)" ::: "memory");
    __builtin_amdgcn_sched_barrier(0);

    // ---- K-quarter partial MFMAs for all 4 btiles, both layers ----
    f32x4 p0[4], p1[4];
#pragma unroll
    for (int bt = 0; bt < 4; ++bt)
#pragma unroll
      for (int g = 0; g < 4; ++g) { p0[bt][g] = 0.f; p1[bt][g] = 0.f; }
#pragma unroll
    for (int s2 = 0; s2 < 2; ++s2)
#pragma unroll
      for (int bt = 0; bt < 4; ++bt)
        p0[bt] = __builtin_amdgcn_mfma_f32_16x16x32_bf16(aIH0[s2], xp[s2][bt], p0[bt], 0, 0, 0);
#pragma unroll
    for (int s = 0; s < 4; ++s)
#pragma unroll
      for (int bt = 0; bt < 4; ++bt) {
        p0[bt] = __builtin_amdgcn_mfma_f32_16x16x32_bf16(aHH0[s], f0[bt][s], p0[bt], 0, 0, 0);
        p1[bt] = __builtin_amdgcn_mfma_f32_16x16x32_bf16(aIH1[s], f0[bt][s], p1[bt], 0, 0, 0);
        p1[bt] = __builtin_amdgcn_mfma_f32_16x16x32_bf16(aHH1[s], f1[bt][s], p1[bt], 0, 0, 0);
      }

    // ---- pass 0: reduce L0 partials across waves, finish layer 0 ----
#pragma unroll
    for (int bt = 0; bt < 4; ++bt) sred[w][bt][lane] = p0[bt];
    __syncthreads();
    if (r < T_) {
      f32x4 s = sred[0][w][lane] + sred[1][w][lane]
              + sred[2][w][lane] + sred[3][w][lane] + bias0v;
      float ig = sigf(s[0]), fg = sigf(s[1]), g2 = tanhf(s[2]), og = sigf(s[3]);
      float cn = fg * c0v + ig * g2;
      c0v = cn;
      st_bf(h0wr + hwof + (size_t)b * 8, f2bf(og * tanhf(cn)));
    }
    __syncthreads();

    // ---- pass 1: reduce L1 partials, finish layer 1 ----
#pragma unroll
    for (int bt = 0; bt < 4; ++bt) sred[w][bt][lane] = p1[bt];
    __syncthreads();
    if (r >= 1) {
      f32x4 s = sred[0][w][lane] + sred[1][w][lane]
              + sred[2][w][lane] + sred[3][w][lane] + bias1v;
      float ig = sigf(s[0]), fg = sigf(s[1]), g2 = tanhf(s[2]), og = sigf(s[3]);
      float cn = fg * c1v + ig * g2;
      c1v = cn;
      float hn = og * tanhf(cn);
      st_bf(h1wr + hwof + (size_t)b * 8, f2bf(hn));
      if (r == T_) st_f32(h1fin + (size_t)b * H_ + jj, hn);
    }

    // ---- flag barrier (R10-verified): one store per WG, poll same-bh group ----
    asm volatile("s_waitcnt vmcnt(0)" ::: "memory");
    __syncthreads();
    if (tid == 0) st_u32(ownf, (unsigned)(r + 1));
    if (r + 1 < T_) xpref(r + 1);   // hide x fetch under the wait
    {
      const unsigned R = (unsigned)(r + 1);
      const unsigned* fl = flags + ((((tid & 127) << 1) | bh) << 5);
      while (ld_u32(fl) < R) __builtin_amdgcn_s_sleep(1);
    }
    __syncthreads();
    asm volatile("" ::: "memory");
  }

  // ---- wait the other bh group, then FC ----
  {
    const unsigned R = (unsigned)(T_ + 1);
    const unsigned* fl = flags + ((((tid & 127) << 1) | (bh ^ 1)) << 5);
    while (ld_u32(fl) < R) __builtin_amdgcn_s_sleep(1);
  }
  __syncthreads();
  asm volatile("" ::: "memory");

  // ---- FC epilogue: WG = batch row, thread = output column ----
  if (wg < B_ && tid < DOUT) {
    const float* hrow = h1fin + (size_t)wg * H_;
    const float* wrow = fcw + (size_t)tid * H_;
    float a = fcb[tid];
    for (int j = 0; j < H_; j += 2) {
      union { unsigned long long q; float f[2]; } c;
      c.q = __hip_atomic_load((const unsigned long long*)(hrow + j),
                              __ATOMIC_RELAXED, __HIP_MEMORY_SCOPE_AGENT);
      a += c.f[0] * wrow[j] + c.f[1] * wrow[j + 1];
    }
    out[(size_t)wg * DOUT + tid] = a;
  }
}

extern "C" void kernel_launch(void* const* d_in, const int* in_sizes, int n_in,
                              void* d_out, int out_size, void* d_ws, size_t ws_size,
                              hipStream_t stream) {
  const float* x    = (const float*)d_in[0];
  const float* wih0 = (const float*)d_in[1];
  const float* whh0 = (const float*)d_in[2];
  const float* bih0 = (const float*)d_in[3];
  const float* bhh0 = (const float*)d_in[4];
  const float* wih1 = (const float*)d_in[5];
  const float* whh1 = (const float*)d_in[6];
  const float* bih1 = (const float*)d_in[7];
  const float* bhh1 = (const float*)d_in[8];
  const float* fcw  = (const float*)d_in[9];
  const float* fcb  = (const float*)d_in[10];
  float* out = (float*)d_out;

  char* wsb = (char*)d_ws;
  bool use_xb = ws_size >= (size_t)XB_OFF + XB_BYTES;
  short* xbw = use_xb ? (short*)(wsb + XB_OFF) : nullptr;
  const short* xb = xbw;

  hipLaunchKernelGGL(lstm_init_kernel, dim3(512), dim3(256), 0, stream, d_ws);
  if (use_xb)
    hipLaunchKernelGGL(xconv_kernel, dim3(T_ * 32), dim3(256), 0, stream, x, xbw);

  void* args[] = { (void*)&x, (void*)&wih0, (void*)&whh0, (void*)&bih0, (void*)&bhh0,
                   (void*)&wih1, (void*)&whh1, (void*)&bih1, (void*)&bhh1,
                   (void*)&fcw, (void*)&fcb, (void*)&xb, (void*)&d_ws, (void*)&out };
  hipLaunchCooperativeKernel((const void*)lstm_coop_kernel,
                             dim3(NWG), dim3(256), args, 0, stream);
}

// Round 14
// 4414.738 us; speedup vs baseline: 1.6408x; 1.6408x over previous
//
#include <hip/hip_runtime.h>

#define B_   128
#define T_   1024
#define DIN  256
#define H_   512
#define DOUT 128
#define NWG  256   // 128 column-groups x 2 batch-halves

typedef __attribute__((ext_vector_type(4))) float f32x4;
typedef __attribute__((ext_vector_type(8))) short bf16x8;
typedef __attribute__((ext_vector_type(4))) short bf16x4;

// ---- ws byte layout ----
#define H0_OFF   0u                      // [2][64][128][8] bf16 = 256KB
#define H1_OFF   (256u << 10)            // [2][64][128][8] bf16 = 256KB
#define FIN_OFF  (512u << 10)            // [128][512] f32 = 256KB
#define FLG_OFF  (768u << 10)            // flags[256] @ 128B stride = 32KB
#define XB_OFF   (800u << 10)            // [1024][32][128][8] bf16 = 64MB
#define XB_BYTES ((size_t)T_ * 32 * 128 * 8 * 2)

__device__ __forceinline__ short f2bf(float f) {
  union { float f; unsigned u; } v; v.f = f;
  unsigned r = v.u + 0x7FFFu + ((v.u >> 16) & 1u);
  return (short)(r >> 16);
}
__device__ __forceinline__ float sigf(float x) { return 1.f / (1.f + __expf(-x)); }

// agent-scope coherent access (bypasses non-coherent per-XCD L2)
__device__ __forceinline__ void st_bf(short* p, short v) {
  __hip_atomic_store((unsigned short*)p, (unsigned short)v,
                     __ATOMIC_RELAXED, __HIP_MEMORY_SCOPE_AGENT);
}
__device__ __forceinline__ void st_f32(float* p, float v) {
  __hip_atomic_store(p, v, __ATOMIC_RELAXED, __HIP_MEMORY_SCOPE_AGENT);
}
__device__ __forceinline__ void st_u32(unsigned* p, unsigned v) {
  __hip_atomic_store(p, v, __ATOMIC_RELAXED, __HIP_MEMORY_SCOPE_AGENT);
}
__device__ __forceinline__ unsigned ld_u32(const unsigned* p) {
  return __hip_atomic_load(p, __ATOMIC_RELAXED, __HIP_MEMORY_SCOPE_AGENT);
}
// coherent 16B load, no wait (caller drains vmcnt before use)
__device__ __forceinline__ void ld16(bf16x8& d, const short* p) {
  asm volatile("global_load_dwordx4 %0, %1, off sc0 sc1" : "=v"(d) : "v"(p));
}

__global__ void lstm_init_kernel(void* ws) {
  int gid = blockIdx.x * blockDim.x + threadIdx.x;   // 131072 threads
  unsigned* p = (unsigned*)ws;                       // h0+h1 = 512KB = 131072 dw
  __hip_atomic_store(p + gid, 0u, __ATOMIC_RELAXED, __HIP_MEMORY_SCOPE_AGENT);
  if (gid < 8192) {                                  // flags 32KB
    unsigned* f = (unsigned*)((char*)ws + FLG_OFF);
    __hip_atomic_store(f + gid, 0u, __ATOMIC_RELAXED, __HIP_MEMORY_SCOPE_AGENT);
  }
}

// x fp32 [B][T][DIN] -> xb bf16 fragment-major [T][32][128][8]
__global__ void xconv_kernel(const float* __restrict__ x, short* __restrict__ xb) {
  int blk = blockIdx.x;            // t*32 + g
  int t = blk >> 5, g = blk & 31;
  int b = threadIdx.x >> 1, hf = (threadIdx.x & 1) * 4;
  f32x4 v = *(const f32x4*)(x + ((size_t)b * T_ + t) * DIN + g * 8 + hf);
  bf16x4 o;
#pragma unroll
  for (int j = 0; j < 4; ++j) o[j] = f2bf(v[j]);
  *(bf16x4*)(xb + ((size_t)(t * 32 + g) * 128 + b) * 8 + hf) = o;
}

__global__ __launch_bounds__(256, 1) void lstm_coop_kernel(
    const float* __restrict__ x,
    const float* __restrict__ wih0, const float* __restrict__ whh0,
    const float* __restrict__ bih0, const float* __restrict__ bhh0,
    const float* __restrict__ wih1, const float* __restrict__ whh1,
    const float* __restrict__ bih1, const float* __restrict__ bhh1,
    const float* __restrict__ fcw,  const float* __restrict__ fcb,
    const short* __restrict__ xb,
    void* __restrict__ ws, float* __restrict__ out)
{
  __shared__ short sWih0[16][264];
  __shared__ short sWhh0[16][520];
  __shared__ short sWih1[16][520];
  __shared__ short sWhh1[16][520];

  const int tid  = threadIdx.x;
  const int wg   = blockIdx.x;
  const int cgid = wg >> 1;
  const int bh   = wg & 1;
  const int j0   = cgid * 4;

  char* wsb = (char*)ws;
  short* h0buf = (short*)(wsb + H0_OFF);
  short* h1buf = (short*)(wsb + H1_OFF);
  float* h1fin = (float*)(wsb + FIN_OFF);
  unsigned* flags = (unsigned*)(wsb + FLG_OFF);
  unsigned* ownf  = flags + wg * 32;

  // weight slices -> LDS (fp32 -> bf16 RNE); row lr = 4*jj + gate
  for (int idx = tid; idx < 16 * DIN; idx += 256) {
    int lr = idx >> 8, k = idx & 255;
    int grow = (lr & 3) * H_ + j0 + (lr >> 2);
    sWih0[lr][k] = f2bf(wih0[(size_t)grow * DIN + k]);
  }
  for (int idx = tid; idx < 16 * H_; idx += 256) {
    int lr = idx >> 9, k = idx & 511;
    int grow = (lr & 3) * H_ + j0 + (lr >> 2);
    sWhh0[lr][k] = f2bf(whh0[(size_t)grow * H_ + k]);
    sWih1[lr][k] = f2bf(wih1[(size_t)grow * H_ + k]);
    sWhh1[lr][k] = f2bf(whh1[(size_t)grow * H_ + k]);
  }
  __syncthreads();

  const int lane = tid & 63;
  const int wid  = tid >> 6;
  const int ln   = lane & 15;               // batch within tile / C col
  const int q    = lane >> 4;               // k-subblock / C row-group (jj)
  const int b    = bh * 64 + wid * 16 + ln; // this lane's batch row
  const int jj   = j0 + q;                  // this lane's h column
  const int hwof = (jj >> 3) * 1024 + (jj & 7);  // write offset (+ b*8)

  float bias0[4], bias1[4];
#pragma unroll
  for (int g = 0; g < 4; ++g) {
    int rr = g * H_ + j0 + q;
    bias0[g] = bih0[rr] + bhh0[rr];
    bias1[g] = bih1[rr] + bhh1[rr];
  }

  // x prefetch (one step ahead, plain cached loads)
  bf16x8 xp[8];
  auto xpref = [&](int t) {
    if (xb) {
      const short* p = xb + ((size_t)(t * 32 + q) * 128 + b) * 8;
#pragma unroll
      for (int ks = 0; ks < 8; ++ks) xp[ks] = *(const bf16x8*)(p + ks * 4096);
    } else {
      const float* xrow = x + ((size_t)b * T_ + t) * DIN + q * 8;
#pragma unroll
      for (int ks = 0; ks < 8; ++ks) {
        f32x4 xa = *(const f32x4*)(xrow + ks * 32);
        f32x4 xc = *(const f32x4*)(xrow + ks * 32 + 4);
#pragma unroll
        for (int j = 0; j < 4; ++j) { xp[ks][j] = f2bf(xa[j]); xp[ks][4 + j] = f2bf(xc[j]); }
      }
    }
  };
  xpref(0);

  float c0v = 0.f, c1v = 0.f;

  for (int r = 0; r <= T_; ++r) {
    const short* h0rd = h0buf + (r & 1) * 65536;
    short*       h0wr = h0buf + ((r + 1) & 1) * 65536;
    const short* h1rd = h1buf + (r & 1) * 65536;
    short*       h1wr = h1buf + ((r + 1) & 1) * 65536;
    const bool doL0 = (r < T_), doL1 = (r >= 1);

    // ---- issue coherent fragment loads (f0 shared by L0-whh0 and L1-wih1) ----
    bf16x8 f0[16], f1[16];
    {
      const short* p0 = h0rd + q * 1024 + (size_t)b * 8;
      const short* p1 = h1rd + q * 1024 + (size_t)b * 8;
#pragma unroll
      for (int ks = 0; ks < 16; ++ks) ld16(f0[ks], p0 + ks * 4096);
#pragma unroll
      for (int ks = 0; ks < 16; ++ks) ld16(f1[ks], p1 + ks * 4096);
    }

    f32x4 a0A, a0B, a1A, a1B;
    a0A[0] = bias0[0]; a0A[1] = bias0[1]; a0A[2] = bias0[2]; a0A[3] = bias0[3];
    a1A[0] = bias1[0]; a1A[1] = bias1[1]; a1A[2] = bias1[2]; a1A[3] = bias1[3];
    a0B[0] = 0.f; a0B[1] = 0.f; a0B[2] = 0.f; a0B[3] = 0.f;
    a1B[0] = 0.f; a1B[1] = 0.f; a1B[2] = 0.f; a1B[3] = 0.f;

    // ---- x-MFMAs (depend only on xp/LDS): overlap with f-load flight ----
    if (doL0) {
#pragma unroll
      for (int ks = 0; ks < 8; ++ks) {
        bf16x8 af = *(const bf16x8*)(&sWih0[ln][ks * 32 + q * 8]);
        if (ks & 1) a0B = __builtin_amdgcn_mfma_f32_16x16x32_bf16(af, xp[ks], a0B, 0, 0, 0);
        else        a0A = __builtin_amdgcn_mfma_f32_16x16x32_bf16(af, xp[ks], a0A, 0, 0, 0);
      }
    }

    asm volatile("s_waitcnt vmcnt(0)" ::: "memory");
    __builtin_amdgcn_sched_barrier(0);
    __builtin_amdgcn_s_setprio(1);

    // ---- f0-consuming MFMAs: L0-whh0 and L1-wih1 interleaved (4 acc chains) ----
    if (doL0 && doL1) {
#pragma unroll
      for (int ks = 0; ks < 16; ++ks) {
        bf16x8 af0 = *(const bf16x8*)(&sWhh0[ln][ks * 32 + q * 8]);
        bf16x8 af1 = *(const bf16x8*)(&sWih1[ln][ks * 32 + q * 8]);
        if (ks & 1) {
          a0B = __builtin_amdgcn_mfma_f32_16x16x32_bf16(af0, f0[ks], a0B, 0, 0, 0);
          a1B = __builtin_amdgcn_mfma_f32_16x16x32_bf16(af1, f0[ks], a1B, 0, 0, 0);
        } else {
          a0A = __builtin_amdgcn_mfma_f32_16x16x32_bf16(af0, f0[ks], a0A, 0, 0, 0);
          a1A = __builtin_amdgcn_mfma_f32_16x16x32_bf16(af1, f0[ks], a1A, 0, 0, 0);
        }
      }
    } else if (doL0) {
#pragma unroll
      for (int ks = 0; ks < 16; ++ks) {
        bf16x8 af0 = *(const bf16x8*)(&sWhh0[ln][ks * 32 + q * 8]);
        if (ks & 1) a0B = __builtin_amdgcn_mfma_f32_16x16x32_bf16(af0, f0[ks], a0B, 0, 0, 0);
        else        a0A = __builtin_amdgcn_mfma_f32_16x16x32_bf16(af0, f0[ks], a0A, 0, 0, 0);
      }
    } else {
#pragma unroll
      for (int ks = 0; ks < 16; ++ks) {
        bf16x8 af1 = *(const bf16x8*)(&sWih1[ln][ks * 32 + q * 8]);
        if (ks & 1) a1B = __builtin_amdgcn_mfma_f32_16x16x32_bf16(af1, f0[ks], a1B, 0, 0, 0);
        else        a1A = __builtin_amdgcn_mfma_f32_16x16x32_bf16(af1, f0[ks], a1A, 0, 0, 0);
      }
    }

    // ---- f1-consuming MFMAs: L1-whh1 ----
    if (doL1) {
#pragma unroll
      for (int ks = 0; ks < 16; ++ks) {
        bf16x8 af = *(const bf16x8*)(&sWhh1[ln][ks * 32 + q * 8]);
        if (ks & 1) a1B = __builtin_amdgcn_mfma_f32_16x16x32_bf16(af, f1[ks], a1B, 0, 0, 0);
        else        a1A = __builtin_amdgcn_mfma_f32_16x16x32_bf16(af, f1[ks], a1A, 0, 0, 0);
      }
    }
    __builtin_amdgcn_s_setprio(0);

    // ---- elementwise + coherent stores ----
    if (doL0) {
      f32x4 acc = a0A + a0B;
      float ig = sigf(acc[0]), fg = sigf(acc[1]), gg = tanhf(acc[2]), og = sigf(acc[3]);
      float cn = fg * c0v + ig * gg;
      c0v = cn;
      st_bf(h0wr + hwof + (size_t)b * 8, f2bf(og * tanhf(cn)));
    }
    if (doL1) {
      f32x4 acc = a1A + a1B;
      float ig = sigf(acc[0]), fg = sigf(acc[1]), gg = tanhf(acc[2]), og = sigf(acc[3]);
      float cn = fg * c1v + ig * gg;
      c1v = cn;
      float hn = og * tanhf(cn);
      st_bf(h1wr + hwof + (size_t)b * 8, f2bf(hn));
      if (r == T_) st_f32(h1fin + (size_t)b * H_ + jj, hn);
    }

    // ---- flag barrier: single store per WG, poll same-bh group's 128 flags ----
    asm volatile("s_waitcnt vmcnt(0)" ::: "memory");
    __syncthreads();
    if (tid == 0) st_u32(ownf, (unsigned)(r + 1));
    if (r + 1 < T_) xpref(r + 1);   // hide x fetch under the wait
    {
      const unsigned R = (unsigned)(r + 1);
      const unsigned* fl = flags + ((((tid & 127) << 1) | bh) << 5);
      while (ld_u32(fl) < R) __builtin_amdgcn_s_sleep(1);
    }
    __syncthreads();
    asm volatile("" ::: "memory");
  }

  // ---- wait the other bh group (h1fin complete chip-wide), then FC ----
  {
    const unsigned R = (unsigned)(T_ + 1);
    const unsigned* fl = flags + ((((tid & 127) << 1) | (bh ^ 1)) << 5);
    while (ld_u32(fl) < R) __builtin_amdgcn_s_sleep(1);
  }
  __syncthreads();
  asm volatile("" ::: "memory");

  // ---- FC epilogue: WG = batch row, thread = output column ----
  if (wg < B_ && tid < DOUT) {
    const float* hrow = h1fin + (size_t)wg * H_;
    const float* wrow = fcw + (size_t)tid * H_;
    float a = fcb[tid];
    for (int j = 0; j < H_; j += 2) {
      union { unsigned long long q; float f[2]; } c;
      c.q = __hip_atomic_load((const unsigned long long*)(hrow + j),
                              __ATOMIC_RELAXED, __HIP_MEMORY_SCOPE_AGENT);
      a += c.f[0] * wrow[j] + c.f[1] * wrow[j + 1];
    }
    out[(size_t)wg * DOUT + tid] = a;
  }
}

extern "C" void kernel_launch(void* const* d_in, const int* in_sizes, int n_in,
                              void* d_out, int out_size, void* d_ws, size_t ws_size,
                              hipStream_t stream) {
  const float* x    = (const float*)d_in[0];
  const float* wih0 = (const float*)d_in[1];
  const float* whh0 = (const float*)d_in[2];
  const float* bih0 = (const float*)d_in[3];
  const float* bhh0 = (const float*)d_in[4];
  const float* wih1 = (const float*)d_in[5];
  const float* whh1 = (const float*)d_in[6];
  const float* bih1 = (const float*)d_in[7];
  const float* bhh1 = (const float*)d_in[8];
  const float* fcw  = (const float*)d_in[9];
  const float* fcb  = (const float*)d_in[10];
  float* out = (float*)d_out;

  char* wsb = (char*)d_ws;
  bool use_xb = ws_size >= (size_t)XB_OFF + XB_BYTES;
  short* xbw = use_xb ? (short*)(wsb + XB_OFF) : nullptr;
  const short* xb = xbw;

  hipLaunchKernelGGL(lstm_init_kernel, dim3(512), dim3(256), 0, stream, d_ws);
  if (use_xb)
    hipLaunchKernelGGL(xconv_kernel, dim3(T_ * 32), dim3(256), 0, stream, x, xbw);

  void* args[] = { (void*)&x, (void*)&wih0, (void*)&whh0, (void*)&bih0, (void*)&bhh0,
                   (void*)&wih1, (void*)&whh1, (void*)&bih1, (void*)&bhh1,
                   (void*)&fcw, (void*)&fcb, (void*)&xb, (void*)&d_ws, (void*)&out };
  hipLaunchCooperativeKernel((const void*)lstm_coop_kernel,
                             dim3(NWG), dim3(256), args, 0, stream);
}

// Round 16
// 4341.764 us; speedup vs baseline: 1.6684x; 1.0168x over previous
//
#include <hip/hip_runtime.h>

#define B_   128
#define T_   1024
#define DIN  256
#define H_   512
#define DOUT 128
#define NWG  256   // 128 column-groups x 2 batch-halves

typedef __attribute__((ext_vector_type(4))) float f32x4;
typedef __attribute__((ext_vector_type(8))) short bf16x8;
typedef __attribute__((ext_vector_type(4))) short bf16x4;

// ---- ws byte layout ----
#define H0_OFF   0u                      // [2][64][128][8] bf16 = 256KB
#define H1_OFF   (256u << 10)            // [2][64][128][8] bf16 = 256KB
#define FIN_OFF  (512u << 10)            // [128][512] f32 = 256KB
#define FLG_OFF  (768u << 10)            // flags[256] @ 128B stride = 32KB
#define XB_OFF   (800u << 10)            // [1024][32][128][8] bf16 = 64MB
#define XB_BYTES ((size_t)T_ * 32 * 128 * 8 * 2)

__device__ __forceinline__ short f2bf(float f) {
  union { float f; unsigned u; } v; v.f = f;
  unsigned r = v.u + 0x7FFFu + ((v.u >> 16) & 1u);
  return (short)(r >> 16);
}
// fast sigmoid / tanh via v_exp_f32 (absmax headroom absorbs small drift)
__device__ __forceinline__ float sigf(float x) {
  return __fdividef(1.f, 1.f + __expf(-x));
}
__device__ __forceinline__ float tanhfast(float x) {
  float e = __expf(-2.f * x);
  return __fdividef(1.f - e, 1.f + e);
}

// agent-scope coherent access (bypasses non-coherent per-XCD L2)
__device__ __forceinline__ void st_bf(short* p, short v) {
  __hip_atomic_store((unsigned short*)p, (unsigned short)v,
                     __ATOMIC_RELAXED, __HIP_MEMORY_SCOPE_AGENT);
}
__device__ __forceinline__ void st_f32(float* p, float v) {
  __hip_atomic_store(p, v, __ATOMIC_RELAXED, __HIP_MEMORY_SCOPE_AGENT);
}
__device__ __forceinline__ void st_u32(unsigned* p, unsigned v) {
  __hip_atomic_store(p, v, __ATOMIC_RELAXED, __HIP_MEMORY_SCOPE_AGENT);
}
__device__ __forceinline__ unsigned ld_u32(const unsigned* p) {
  return __hip_atomic_load(p, __ATOMIC_RELAXED, __HIP_MEMORY_SCOPE_AGENT);
}
// coherent 16B load, no wait (caller drains vmcnt before use)
__device__ __forceinline__ void ld16(bf16x8& d, const short* p) {
  asm volatile("global_load_dwordx4 %0, %1, off sc0 sc1" : "=v"(d) : "v"(p));
}

__global__ void lstm_init_kernel(void* ws) {
  int gid = blockIdx.x * blockDim.x + threadIdx.x;   // 131072 threads
  unsigned* p = (unsigned*)ws;                       // h0+h1 = 512KB = 131072 dw
  __hip_atomic_store(p + gid, 0u, __ATOMIC_RELAXED, __HIP_MEMORY_SCOPE_AGENT);
  if (gid < 8192) {                                  // flags 32KB
    unsigned* f = (unsigned*)((char*)ws + FLG_OFF);
    __hip_atomic_store(f + gid, 0u, __ATOMIC_RELAXED, __HIP_MEMORY_SCOPE_AGENT);
  }
}

// x fp32 [B][T][DIN] -> xb bf16 fragment-major [T][32][128][8]
__global__ void xconv_kernel(const float* __restrict__ x, short* __restrict__ xb) {
  int blk = blockIdx.x;            // t*32 + g
  int t = blk >> 5, g = blk & 31;
  int b = threadIdx.x >> 1, hf = (threadIdx.x & 1) * 4;
  f32x4 v = *(const f32x4*)(x + ((size_t)b * T_ + t) * DIN + g * 8 + hf);
  bf16x4 o;
#pragma unroll
  for (int j = 0; j < 4; ++j) o[j] = f2bf(v[j]);
  *(bf16x4*)(xb + ((size_t)(t * 32 + g) * 128 + b) * 8 + hf) = o;
}

__global__ __launch_bounds__(256, 1) void lstm_coop_kernel(
    const float* __restrict__ x,
    const float* __restrict__ wih0, const float* __restrict__ whh0,
    const float* __restrict__ bih0, const float* __restrict__ bhh0,
    const float* __restrict__ wih1, const float* __restrict__ whh1,
    const float* __restrict__ bih1, const float* __restrict__ bhh1,
    const float* __restrict__ fcw,  const float* __restrict__ fcb,
    const short* __restrict__ xb,
    void* __restrict__ ws, float* __restrict__ out)
{
  __shared__ short sWih0[16][264];
  __shared__ short sWhh0[16][520];
  __shared__ short sWih1[16][520];
  __shared__ short sWhh1[16][520];

  const int tid  = threadIdx.x;
  const int wg   = blockIdx.x;
  const int cgid = wg >> 1;
  const int bh   = wg & 1;
  const int j0   = cgid * 4;

  char* wsb = (char*)ws;
  short* h0buf = (short*)(wsb + H0_OFF);
  short* h1buf = (short*)(wsb + H1_OFF);
  float* h1fin = (float*)(wsb + FIN_OFF);
  unsigned* flags = (unsigned*)(wsb + FLG_OFF);
  unsigned* ownf  = flags + wg * 32;

  // weight slices -> LDS (fp32 -> bf16 RNE); row lr = 4*jj + gate
  for (int idx = tid; idx < 16 * DIN; idx += 256) {
    int lr = idx >> 8, k = idx & 255;
    int grow = (lr & 3) * H_ + j0 + (lr >> 2);
    sWih0[lr][k] = f2bf(wih0[(size_t)grow * DIN + k]);
  }
  for (int idx = tid; idx < 16 * H_; idx += 256) {
    int lr = idx >> 9, k = idx & 511;
    int grow = (lr & 3) * H_ + j0 + (lr >> 2);
    sWhh0[lr][k] = f2bf(whh0[(size_t)grow * H_ + k]);
    sWih1[lr][k] = f2bf(wih1[(size_t)grow * H_ + k]);
    sWhh1[lr][k] = f2bf(whh1[(size_t)grow * H_ + k]);
  }
  __syncthreads();

  const int lane = tid & 63;
  const int wid  = tid >> 6;
  const int ln   = lane & 15;               // batch within tile / C col
  const int q    = lane >> 4;               // k-subblock / C row-group (jj)
  const int b    = bh * 64 + wid * 16 + ln; // this lane's batch row
  const int jj   = j0 + q;                  // this lane's h column
  const int hwof = (jj >> 3) * 1024 + (jj & 7);  // write offset (+ b*8)

  float bias0[4], bias1[4];
#pragma unroll
  for (int g = 0; g < 4; ++g) {
    int rr = g * H_ + j0 + q;
    bias0[g] = bih0[rr] + bhh0[rr];
    bias1[g] = bih1[rr] + bhh1[rr];
  }

  // x prefetch (one step ahead, plain cached loads)
  bf16x8 xp[8];
  auto xpref = [&](int t) {
    if (xb) {
      const short* p = xb + ((size_t)(t * 32 + q) * 128 + b) * 8;
#pragma unroll
      for (int ks = 0; ks < 8; ++ks) xp[ks] = *(const bf16x8*)(p + ks * 4096);
    } else {
      const float* xrow = x + ((size_t)b * T_ + t) * DIN + q * 8;
#pragma unroll
      for (int ks = 0; ks < 8; ++ks) {
        f32x4 xa = *(const f32x4*)(xrow + ks * 32);
        f32x4 xc = *(const f32x4*)(xrow + ks * 32 + 4);
#pragma unroll
        for (int j = 0; j < 4; ++j) { xp[ks][j] = f2bf(xa[j]); xp[ks][4 + j] = f2bf(xc[j]); }
      }
    }
  };
  xpref(0);

  float c0v = 0.f, c1v = 0.f;

  for (int r = 0; r <= T_; ++r) {
    const short* h0rd = h0buf + (r & 1) * 65536;
    short*       h0wr = h0buf + ((r + 1) & 1) * 65536;
    const short* h1rd = h1buf + (r & 1) * 65536;
    short*       h1wr = h1buf + ((r + 1) & 1) * 65536;
    const bool doL0 = (r < T_), doL1 = (r >= 1);

    // ---- issue coherent fragment loads (f0 shared by L0-whh0 and L1-wih1) ----
    bf16x8 f0[16], f1[16];
    {
      const short* p0 = h0rd + q * 1024 + (size_t)b * 8;
      const short* p1 = h1rd + q * 1024 + (size_t)b * 8;
#pragma unroll
      for (int ks = 0; ks < 16; ++ks) ld16(f0[ks], p0 + ks * 4096);
#pragma unroll
      for (int ks = 0; ks < 16; ++ks) ld16(f1[ks], p1 + ks * 4096);
    }

    f32x4 a0A, a0B, a1A, a1B;
    a0A[0] = bias0[0]; a0A[1] = bias0[1]; a0A[2] = bias0[2]; a0A[3] = bias0[3];
    a1A[0] = bias1[0]; a1A[1] = bias1[1]; a1A[2] = bias1[2]; a1A[3] = bias1[3];
    a0B[0] = 0.f; a0B[1] = 0.f; a0B[2] = 0.f; a0B[3] = 0.f;
    a1B[0] = 0.f; a1B[1] = 0.f; a1B[2] = 0.f; a1B[3] = 0.f;

    // ---- x-MFMAs (depend only on xp/LDS): overlap with f-load flight ----
    if (doL0) {
#pragma unroll
      for (int ks = 0; ks < 8; ++ks) {
        bf16x8 af = *(const bf16x8*)(&sWih0[ln][ks * 32 + q * 8]);
        if (ks & 1) a0B = __builtin_amdgcn_mfma_f32_16x16x32_bf16(af, xp[ks], a0B, 0, 0, 0);
        else        a0A = __builtin_amdgcn_mfma_f32_16x16x32_bf16(af, xp[ks], a0A, 0, 0, 0);
      }
    }

    asm volatile("s_waitcnt vmcnt(0)" ::: "memory");
    __builtin_amdgcn_sched_barrier(0);
    __builtin_amdgcn_s_setprio(1);

    // ---- f0-consuming MFMAs: L0-whh0 and L1-wih1 interleaved (4 acc chains) ----
    if (doL0 && doL1) {
#pragma unroll
      for (int ks = 0; ks < 16; ++ks) {
        bf16x8 af0 = *(const bf16x8*)(&sWhh0[ln][ks * 32 + q * 8]);
        bf16x8 af1 = *(const bf16x8*)(&sWih1[ln][ks * 32 + q * 8]);
        if (ks & 1) {
          a0B = __builtin_amdgcn_mfma_f32_16x16x32_bf16(af0, f0[ks], a0B, 0, 0, 0);
          a1B = __builtin_amdgcn_mfma_f32_16x16x32_bf16(af1, f0[ks], a1B, 0, 0, 0);
        } else {
          a0A = __builtin_amdgcn_mfma_f32_16x16x32_bf16(af0, f0[ks], a0A, 0, 0, 0);
          a1A = __builtin_amdgcn_mfma_f32_16x16x32_bf16(af1, f0[ks], a1A, 0, 0, 0);
        }
      }
    } else if (doL0) {
#pragma unroll
      for (int ks = 0; ks < 16; ++ks) {
        bf16x8 af0 = *(const bf16x8*)(&sWhh0[ln][ks * 32 + q * 8]);
        if (ks & 1) a0B = __builtin_amdgcn_mfma_f32_16x16x32_bf16(af0, f0[ks], a0B, 0, 0, 0);
        else        a0A = __builtin_amdgcn_mfma_f32_16x16x32_bf16(af0, f0[ks], a0A, 0, 0, 0);
      }
    } else {
#pragma unroll
      for (int ks = 0; ks < 16; ++ks) {
        bf16x8 af1 = *(const bf16x8*)(&sWih1[ln][ks * 32 + q * 8]);
        if (ks & 1) a1B = __builtin_amdgcn_mfma_f32_16x16x32_bf16(af1, f0[ks], a1B, 0, 0, 0);
        else        a1A = __builtin_amdgcn_mfma_f32_16x16x32_bf16(af1, f0[ks], a1A, 0, 0, 0);
      }
    }

    // ---- f1-consuming MFMAs: L1-whh1 ----
    if (doL1) {
#pragma unroll
      for (int ks = 0; ks < 16; ++ks) {
        bf16x8 af = *(const bf16x8*)(&sWhh1[ln][ks * 32 + q * 8]);
        if (ks & 1) a1B = __builtin_amdgcn_mfma_f32_16x16x32_bf16(af, f1[ks], a1B, 0, 0, 0);
        else        a1A = __builtin_amdgcn_mfma_f32_16x16x32_bf16(af, f1[ks], a1A, 0, 0, 0);
      }
    }
    __builtin_amdgcn_s_setprio(0);

    // ---- elementwise (fast transcendentals) + coherent stores ----
    if (doL0) {
      f32x4 acc = a0A + a0B;
      float ig = sigf(acc[0]), fg = sigf(acc[1]);
      float gg = tanhfast(acc[2]), og = sigf(acc[3]);
      float cn = fg * c0v + ig * gg;
      c0v = cn;
      st_bf(h0wr + hwof + (size_t)b * 8, f2bf(og * tanhfast(cn)));
    }
    if (doL1) {
      f32x4 acc = a1A + a1B;
      float ig = sigf(acc[0]), fg = sigf(acc[1]);
      float gg = tanhfast(acc[2]), og = sigf(acc[3]);
      float cn = fg * c1v + ig * gg;
      c1v = cn;
      float hn = og * tanhfast(cn);
      st_bf(h1wr + hwof + (size_t)b * 8, f2bf(hn));
      if (r == T_) st_f32(h1fin + (size_t)b * H_ + jj, hn);
    }

    // ---- flag barrier: single store per WG, poll same-bh group's 128 flags ----
    asm volatile("s_waitcnt vmcnt(0)" ::: "memory");
    __syncthreads();
    if (tid == 0) st_u32(ownf, (unsigned)(r + 1));
    if (r + 1 < T_) xpref(r + 1);   // hide x fetch under the wait
    {
      const unsigned R = (unsigned)(r + 1);
      const unsigned* fl = flags + ((((tid & 127) << 1) | bh) << 5);
      while (ld_u32(fl) < R) __builtin_amdgcn_s_sleep(1);
    }
    __syncthreads();
    asm volatile("" ::: "memory");
  }

  // ---- wait the other bh group (h1fin complete chip-wide), then FC ----
  {
    const unsigned R = (unsigned)(T_ + 1);
    const unsigned* fl = flags + ((((tid & 127) << 1) | (bh ^ 1)) << 5);
    while (ld_u32(fl) < R) __builtin_amdgcn_s_sleep(1);
  }
  __syncthreads();
  asm volatile("" ::: "memory");

  // ---- FC epilogue: WG = batch row, thread = output column ----
  if (wg < B_ && tid < DOUT) {
    const float* hrow = h1fin + (size_t)wg * H_;
    const float* wrow = fcw + (size_t)tid * H_;
    float a = fcb[tid];
    for (int j = 0; j < H_; j += 2) {
      union { unsigned long long q; float f[2]; } c;
      c.q = __hip_atomic_load((const unsigned long long*)(hrow + j),
                              __ATOMIC_RELAXED, __HIP_MEMORY_SCOPE_AGENT);
      a += c.f[0] * wrow[j] + c.f[1] * wrow[j + 1];
    }
    out[(size_t)wg * DOUT + tid] = a;
  }
}

extern "C" void kernel_launch(void* const* d_in, const int* in_sizes, int n_in,
                              void* d_out, int out_size, void* d_ws, size_t ws_size,
                              hipStream_t stream) {
  const float* x    = (const float*)d_in[0];
  const float* wih0 = (const float*)d_in[1];
  const float* whh0 = (const float*)d_in[2];
  const float* bih0 = (const float*)d_in[3];
  const float* bhh0 = (const float*)d_in[4];
  const float* wih1 = (const float*)d_in[5];
  const float* whh1 = (const float*)d_in[6];
  const float* bih1 = (const float*)d_in[7];
  const float* bhh1 = (const float*)d_in[8];
  const float* fcw  = (const float*)d_in[9];
  const float* fcb  = (const float*)d_in[10];
  float* out = (float*)d_out;

  char* wsb = (char*)d_ws;
  bool use_xb = ws_size >= (size_t)XB_OFF + XB_BYTES;
  short* xbw = use_xb ? (short*)(wsb + XB_OFF) : nullptr;
  const short* xb = xbw;

  hipLaunchKernelGGL(lstm_init_kernel, dim3(512), dim3(256), 0, stream, d_ws);
  if (use_xb)
    hipLaunchKernelGGL(xconv_kernel, dim3(T_ * 32), dim3(256), 0, stream, x, xbw);

  void* args[] = { (void*)&x, (void*)&wih0, (void*)&whh0, (void*)&bih0, (void*)&bhh0,
                   (void*)&wih1, (void*)&whh1, (void*)&bih1, (void*)&bhh1,
                   (void*)&fcw, (void*)&fcb, (void*)&xb, (void*)&d_ws, (void*)&out };
  hipLaunchCooperativeKernel((const void*)lstm_coop_kernel,
                             dim3(NWG), dim3(256), args, 0, stream);
}